// Round 17
// baseline (372.867 us; speedup 1.0000x reference)
//
#include <hip/hip_runtime.h>
#include <hip/hip_fp16.h>

#define N_NODES 50000
#define NEDGE   500000
#define HEADS   8
#define FEAT    16
#define HF      128   // HEADS*FEAT
#define UST     64    // u row stride in FLOATS: 128 fp16 = 256B = 2 aligned cache lines

// ---- async global->LDS, 16B per lane; dest = wave-uniform base + lane*16 ----
// offset arg ALWAYS 0: R12 proved non-zero imm offsets corrupt data on gfx950.
__device__ __forceinline__ void gload_lds16(const float* gsrc, float* ldst) {
  __builtin_amdgcn_global_load_lds(
      (const __attribute__((address_space(1))) unsigned int*)gsrc,
      (__attribute__((address_space(3))) unsigned int*)ldst, 16, 0, 0);
}

__device__ __forceinline__ unsigned pkh2(float a, float b) {
  __half2 h = __floats2half2_rn(a, b);
  return *(unsigned*)&h;
}

// ========== GEMM: u(fp16) = x[idx] @ W[128,128] + b ; grid (391, 2) ==========
// R16 structure + SPLIT-COLUMN mapping: thread covers cols {cg*4..+3, 64+cg*4..+3}
// so each W float4 LDS read is 16B-strided across 16 lanes -> 2-way bank access
// (free) instead of the old cg*8 mapping's 32B stride -> 4-way conflict (1.58x;
// measured 6.4M conflict cycles). Counted-vmcnt sync kept (R16, neutral-but-safe).
__global__ __launch_bounds__(256)
void gemm_v128_kernel(const float* __restrict__ xa, const int* __restrict__ idxa,
                      const float* __restrict__ xb, const int* __restrict__ idxb,
                      const float* __restrict__ W, const float* __restrict__ bias,
                      float* __restrict__ ua, float* __restrict__ ub, int nrows) {
  const int side = blockIdx.y;
  const float* x  = side ? xb : xa;
  const int* idx  = side ? idxb : idxa;
  const float* Wp = W + (size_t)side * 128 * HF;
  const float* bp = bias + side * HF;
  float* uout = side ? ub : ua;

  __shared__ float A[2][128 * 16];    // 8 KB each
  __shared__ float Wl[2][16 * 128];   // 8 KB each  (32 KB total)
  const int tid = threadIdx.x;
  const int w   = tid >> 6;           // wave id 0..3
  const int rg  = tid >> 4;           // rows rg*8..+7 (0..15)
  const int cg  = tid & 15;           // cols {cg*4..+3} and {64+cg*4..+3}
  const int row0 = blockIdx.x * 128;

  const int sr = tid >> 2, sc = (tid & 3) * 4;
  const int wk = tid >> 5, wc = (tid & 31) * 4;
  int r0 = row0 + sr, r1 = row0 + 64 + sr;
  int g0 = (r0 < nrows) ? (idx ? idx[r0] : r0) : 0;
  int g1 = (r1 < nrows) ? (idx ? idx[r1] : r1) : 0;
  const float* a0src = x + (size_t)g0 * 128 + sc;
  const float* a1src = x + (size_t)g1 * 128 + sc;
  const float* w0src = Wp + (size_t)wk * HF + wc;   // rows 0-7; rows 8-15 = +1024 floats

  float acc[8][8];
  {
    const float4 b0 = *(const float4*)&bp[cg * 4];        // cols cg*4..+3
    const float4 b1 = *(const float4*)&bp[64 + cg * 4];   // cols 64+cg*4..+3
    #pragma unroll
    for (int i = 0; i < 8; ++i) {
      acc[i][0] = b0.x; acc[i][1] = b0.y; acc[i][2] = b0.z; acc[i][3] = b0.w;
      acc[i][4] = b1.x; acc[i][5] = b1.y; acc[i][6] = b1.z; acc[i][7] = b1.w;
    }
  }

  // prologue: stage chunk 0
  gload_lds16(a0src, &A[0][w * 256]);
  gload_lds16(a1src, &A[0][1024 + w * 256]);
  gload_lds16(w0src, &Wl[0][w * 256]);
  gload_lds16(w0src + 1024, &Wl[0][1024 + w * 256]);

  int buf = 0;
  for (int c = 0; c < 8; ++c) {
    if (c < 7) {
      const int kc = (c + 1) * 16;
      gload_lds16(a0src + kc,                      &A[buf ^ 1][w * 256]);
      gload_lds16(a1src + kc,                      &A[buf ^ 1][1024 + w * 256]);
      gload_lds16(w0src + (size_t)kc * HF,         &Wl[buf ^ 1][w * 256]);
      gload_lds16(w0src + (size_t)kc * HF + 1024,  &Wl[buf ^ 1][1024 + w * 256]);
      asm volatile("s_waitcnt vmcnt(4)" ::: "memory");
    } else {
      asm volatile("s_waitcnt vmcnt(0)" ::: "memory");
    }
    asm volatile("s_barrier" ::: "memory");
    #pragma unroll
    for (int k2 = 0; k2 < 8; ++k2) {
      float4 w0l = *(float4*)&Wl[buf][(k2 * 2 + 0) * 128 + cg * 4];
      float4 w0h = *(float4*)&Wl[buf][(k2 * 2 + 0) * 128 + 64 + cg * 4];
      float4 w1l = *(float4*)&Wl[buf][(k2 * 2 + 1) * 128 + cg * 4];
      float4 w1h = *(float4*)&Wl[buf][(k2 * 2 + 1) * 128 + 64 + cg * 4];
      #pragma unroll
      for (int i = 0; i < 8; ++i) {
        float2 av = *(float2*)&A[buf][(rg * 8 + i) * 16 + k2 * 2];
        acc[i][0] += av.x * w0l.x + av.y * w1l.x;
        acc[i][1] += av.x * w0l.y + av.y * w1l.y;
        acc[i][2] += av.x * w0l.z + av.y * w1l.z;
        acc[i][3] += av.x * w0l.w + av.y * w1l.w;
        acc[i][4] += av.x * w0h.x + av.y * w1h.x;
        acc[i][5] += av.x * w0h.y + av.y * w1h.y;
        acc[i][6] += av.x * w0h.z + av.y * w1h.z;
        acc[i][7] += av.x * w0h.w + av.y * w1h.w;
      }
    }
    asm volatile("s_barrier" ::: "memory");
    buf ^= 1;
  }
  #pragma unroll
  for (int i = 0; i < 8; ++i) {
    int rr = row0 + rg * 8 + i;
    if (rr < nrows) {
      uint2 lo, hi;
      lo.x = pkh2(acc[i][0], acc[i][1]); lo.y = pkh2(acc[i][2], acc[i][3]);
      hi.x = pkh2(acc[i][4], acc[i][5]); hi.y = pkh2(acc[i][6], acc[i][7]);
      *(uint2*)&uout[(size_t)rr * UST + cg * 2]      = lo;   // fp16 cols cg*4..+3
      *(uint2*)&uout[(size_t)rr * UST + 32 + cg * 2] = hi;   // fp16 cols 64+cg*4..+3
    }
  }
}

// ================= fold Wf = Wv @ Wqk [Kx,8], bias bf = bv@Wqk + bqk =================
__global__ __launch_bounds__(256)
void fold_kernel(const float* __restrict__ l1_Wv, const float* __restrict__ l1_bv,
                 const float* __restrict__ l1_Wq, const float* __restrict__ l1_bq,
                 const float* __restrict__ l1_Wk, const float* __restrict__ l1_bk,
                 const float* __restrict__ l2_Wv, const float* __restrict__ l2_bv,
                 const float* __restrict__ l2_Wq, const float* __restrict__ l2_bq,
                 const float* __restrict__ l2_Wk, const float* __restrict__ l2_bk,
                 float* __restrict__ outbuf) {
  int b = blockIdx.x;
  int layer = b >> 2, rel = (b >> 1) & 1, qk = b & 1;
  int Kx = (layer == 0) ? 128 : 16;
  const float* Wv = ((layer == 0) ? l1_Wv : l2_Wv) + (size_t)rel * Kx * HF;
  const float* bv = ((layer == 0) ? l1_bv : l2_bv) + rel * HF;
  const float* Wqk = ((layer == 0) ? (qk ? l1_Wk : l1_Wq) : (qk ? l2_Wk : l2_Wq)) + (size_t)rel * HF * 8;
  const float* bqk = ((layer == 0) ? (qk ? l1_bk : l1_bq) : (qk ? l2_bk : l2_bq)) + rel * 8;
  float* o = outbuf + (size_t)b * 1040;
  for (int t = threadIdx.x; t < Kx * 8; t += 256) {
    int row = t >> 3, c = t & 7;
    float acc = 0.f;
    for (int j = 0; j < HF; ++j) acc += Wv[row * HF + j] * Wqk[j * 8 + c];
    o[t] = acc;
  }
  for (int t = threadIdx.x; t < 8; t += 256) {
    float acc = bqk[t];
    for (int j = 0; j < HF; ++j) acc += bv[j] * Wqk[j * 8 + t];
    o[Kx * 8 + t] = acc;
  }
}

// ========== L1 qk projections: k -> kb[N,8] fp32, q -> qout[N,8]; grid (nb,2) ==========
template<int K, int SA>
__global__ __launch_bounds__(256)
void qk_kernel(const float* __restrict__ xa, const int* __restrict__ idxa,
               const float* __restrict__ xb, const int* __restrict__ idxb,
               const float* __restrict__ WfkA, const float* __restrict__ WfqA,
               const float* __restrict__ WfkB, const float* __restrict__ WfqB,
               float* __restrict__ kA, float* __restrict__ kB,
               float* __restrict__ qA, float* __restrict__ qB, int nrows) {
  const int side = blockIdx.y;
  const float* x   = side ? xb : xa;
  const int* idx   = side ? idxb : idxa;
  const float* Wfk = side ? WfkB : WfkA;
  const float* Wfq = side ? WfqB : WfqA;
  float* kout = side ? kB : kA;
  float* qout = side ? qB : qA;

  __shared__ float x_lds[64 * SA];
  __shared__ float Wk_lds[K * 8 + 8];
  __shared__ float Wq_lds[K * 8 + 8];
  const int tid = threadIdx.x;
  const int row0 = blockIdx.x * 64;
  for (int i = tid; i < K * 8 + 8; i += 256) { Wk_lds[i] = Wfk[i]; Wq_lds[i] = Wfq[i]; }
  {
    int rr = row0 + (tid >> 2);
    int g = (rr < nrows) ? (idx ? idx[rr] : rr) : -1;
    const float* xp = (g >= 0) ? x + (size_t)g * K : nullptr;
    #pragma unroll
    for (int j = 0; j < K / 16; ++j) {
      int c = (tid & 3) * 4 + j * 16;
      float4 v = xp ? *(const float4*)(xp + c) : make_float4(0.f,0.f,0.f,0.f);
      *(float4*)&x_lds[(tid >> 2) * SA + c] = v;
    }
  }
  __syncthreads();
  const int r = tid >> 2, grp = tid & 3;
  const float* wsel = (grp < 2) ? Wk_lds : Wq_lds;
  const int c0 = (grp & 1) * 4;
  float acc[4];
  #pragma unroll
  for (int cc = 0; cc < 4; ++cc) acc[cc] = wsel[K * 8 + c0 + cc];
  #pragma unroll 4
  for (int k4 = 0; k4 < K / 4; ++k4) {
    float4 a4 = *(float4*)&x_lds[r * SA + k4 * 4];
    float av[4] = {a4.x, a4.y, a4.z, a4.w};
    #pragma unroll
    for (int j = 0; j < 4; ++j) {
      float4 w = *(float4*)&wsel[(k4 * 4 + j) * 8 + c0];
      acc[0] += av[j] * w.x; acc[1] += av[j] * w.y;
      acc[2] += av[j] * w.z; acc[3] += av[j] * w.w;
    }
  }
  int rr = row0 + r;
  if (rr < nrows) {
    if (grp < 2)
      *(float4*)&kout[(size_t)rr * 8 + grp * 4] = *(float4*)acc;
    else
      *(float4*)&qout[(size_t)rr * 8 + (grp - 2) * 4] = *(float4*)acc;
  }
}

// ================= batched CSR build (both relations at once) =================
__global__ __launch_bounds__(256)
void hist2_kernel(const int* __restrict__ dst0, const int* __restrict__ dst1,
                  int* __restrict__ cnt) {
  int e = blockIdx.x * 256 + threadIdx.x;
  if (e < NEDGE) atomicAdd(&cnt[dst0[e]], 1);
  else if (e < 2 * NEDGE) atomicAdd(&cnt[N_NODES + dst1[e - NEDGE]], 1);
}

__global__ __launch_bounds__(256)
void scan_bsum_kernel(const int* __restrict__ cnt, int* __restrict__ bsum, int n) {
  __shared__ int s[256];
  int i = blockIdx.x * 256 + threadIdx.x;
  s[threadIdx.x] = (i < n) ? cnt[i] : 0;
  __syncthreads();
  for (int o = 128; o > 0; o >>= 1) {
    if (threadIdx.x < o) s[threadIdx.x] += s[threadIdx.x + o];
    __syncthreads();
  }
  if (threadIdx.x == 0) bsum[blockIdx.x] = s[0];
}

__global__ __launch_bounds__(512)
void scan_offsets_kernel(int* __restrict__ bsum, int nb) {
  __shared__ int s[512];
  int t = threadIdx.x;
  s[t] = (t < nb) ? bsum[t] : 0;
  __syncthreads();
  for (int o = 1; o < 512; o <<= 1) {
    int v = (t >= o) ? s[t - o] : 0;
    __syncthreads();
    s[t] += v;
    __syncthreads();
  }
  if (t < nb) bsum[t] = (t == 0) ? 0 : s[t - 1];
}

__global__ __launch_bounds__(256)
void scan_final_kernel(const int* __restrict__ cnt, const int* __restrict__ boff,
                       int* __restrict__ row_start, int n) {
  __shared__ int s[256];
  int t = threadIdx.x, i = blockIdx.x * 256 + t;
  int v = (i < n) ? cnt[i] : 0;
  s[t] = v;
  __syncthreads();
  for (int o = 1; o < 256; o <<= 1) {
    int w = (t >= o) ? s[t - o] : 0;
    __syncthreads();
    s[t] += w;
    __syncthreads();
  }
  if (i < n)  row_start[i] = boff[blockIdx.x] + s[t] - v;
  if (i == n - 1) row_start[n] = boff[blockIdx.x] + s[t];
}

__global__ __launch_bounds__(256)
void csr_scatter2_kernel(const int* __restrict__ s0, const int* __restrict__ d0,
                         const int* __restrict__ s1, const int* __restrict__ d1,
                         const int* __restrict__ rs, int* __restrict__ fill,
                         int* __restrict__ cs) {
  int e = blockIdx.x * 256 + threadIdx.x;
  if (e >= 2 * NEDGE) return;
  int rel = (e >= NEDGE);
  int ee = rel ? e - NEDGE : e;
  int d = rel ? d1[ee] : d0[ee];
  int s = rel ? s1[ee] : s0[ee];
  int key = rel * N_NODES + d;
  int pos = rs[key] + atomicAdd(&fill[key], 1);
  cs[pos] = s;
}

// ========= L1 GAT aggregation + FUSED L2 qk projections =========
// 32 lanes/node, fp16 u (uint2/lane), separate fp32 k. After the head-mean
// (all lanes hold the ELU'd x feat-group l&3), shfl-broadcast the 16 x values
// and lanes 0-15 compute this node's 8 k2 + 8 q L2 projections (replaces the
// qk16 dispatch). q tables are read (L1) then overwritten (L2) by the SAME
// node-group only -> no cross-group race. Empty nodes: x=0 -> bias (correct).
__global__ __launch_bounds__(256)
void node_agg2_kernel(const int* __restrict__ rs, const int* __restrict__ cs,
                      const float* __restrict__ u0, const float* __restrict__ u1,
                      const float* __restrict__ kb0, const float* __restrict__ kb1,
                      const float* __restrict__ qt0, const float* __restrict__ qt1,
                      float* __restrict__ out0, float* __restrict__ out1,
                      const float* __restrict__ WkR0, const float* __restrict__ WqR0,
                      const float* __restrict__ WkR1, const float* __restrict__ WqR1,
                      float* __restrict__ k2o0, float* __restrict__ q2o0,
                      float* __restrict__ k2o1, float* __restrict__ q2o1) {
  __shared__ float Wtab[4][136];
  {
    const float* srcs[4] = {WkR0, WqR0, WkR1, WqR1};
    for (int i = threadIdx.x; i < 4 * 136; i += 256)
      Wtab[i / 136][i % 136] = srcs[i / 136][i % 136];
  }
  __syncthreads();

  int grp  = (blockIdx.x * 256 + threadIdx.x) >> 5;
  int lane = threadIdx.x & 31;
  if (grp >= 2 * N_NODES) return;   // never triggers (grid exact); after barrier
  int rel = grp >= N_NODES;
  int node = grp - (rel ? N_NODES : 0);
  const float* ut = rel ? u1 : u0;
  const float* kb = rel ? kb1 : kb0;
  const float* qt = rel ? qt1 : qt0;
  float* out      = rel ? out1 : out0;

  int e0 = rs[grp], e1 = rs[grp + 1];
  const int hd = lane >> 2;
  float qh = qt[node * 8 + hd];
  float den = 0.f;
  float4 acc = make_float4(0.f, 0.f, 0.f, 0.f);

  int e = e0;
  for (; e + 7 < e1; e += 8) {
    int s[8];
    #pragma unroll
    for (int j = 0; j < 8; ++j) s[j] = cs[e + j];
    uint2 uv[8]; float kv[8];
    #pragma unroll
    for (int j = 0; j < 8; ++j) {
      uv[j] = *(const uint2*)((const char*)(ut + (size_t)s[j] * UST) + lane * 8);
      kv[j] = kb[s[j] * 8 + hd];
    }
    #pragma unroll
    for (int j = 0; j < 8; ++j) {
      float sc = kv[j] + qh; sc = sc > 0.f ? sc : 0.2f * sc;
      float ex = __expf(sc);
      den += ex;
      float2 f01 = __half22float2(*(__half2*)&uv[j].x);
      float2 f23 = __half22float2(*(__half2*)&uv[j].y);
      acc.x += ex * f01.x; acc.y += ex * f01.y;
      acc.z += ex * f23.x; acc.w += ex * f23.y;
    }
  }
  for (; e < e1; ++e) {
    int s0 = cs[e];
    uint2 uvv = *(const uint2*)((const char*)(ut + (size_t)s0 * UST) + lane * 8);
    float kv = kb[s0 * 8 + hd];
    float sc = kv + qh; sc = sc > 0.f ? sc : 0.2f * sc;
    float ex = __expf(sc);
    den += ex;
    float2 f01 = __half22float2(*(__half2*)&uvv.x);
    float2 f23 = __half22float2(*(__half2*)&uvv.y);
    acc.x += ex * f01.x; acc.y += ex * f01.y;
    acc.z += ex * f23.x; acc.w += ex * f23.y;
  }
  float inv = den > 0.f ? 1.f / den : 0.f;
  float4 r = make_float4(acc.x * inv, acc.y * inv, acc.z * inv, acc.w * inv);
  #pragma unroll
  for (int m = 4; m <= 16; m <<= 1) {
    r.x += __shfl_xor(r.x, m); r.y += __shfl_xor(r.y, m);
    r.z += __shfl_xor(r.z, m); r.w += __shfl_xor(r.w, m);
  }
  r.x *= 0.125f; r.y *= 0.125f; r.z *= 0.125f; r.w *= 0.125f;
  // ELU (L1 always)
  r.x = r.x > 0.f ? r.x : expm1f(r.x);
  r.y = r.y > 0.f ? r.y : expm1f(r.y);
  r.z = r.z > 0.f ? r.z : expm1f(r.z);
  r.w = r.w > 0.f ? r.w : expm1f(r.w);
  if (lane < 4) *(float4*)&out[(size_t)node * FEAT + lane * 4] = r;

  // ---- fused L2 qk: x row via shfl broadcast (feat group g held at lanes l&3==g) ----
  const int b32 = threadIdx.x & 32;   // 32-group base within wave
  float xrow[16];
  #pragma unroll
  for (int g = 0; g < 4; ++g) {
    xrow[g * 4 + 0] = __shfl(r.x, b32 + g, 64);
    xrow[g * 4 + 1] = __shfl(r.y, b32 + g, 64);
    xrow[g * 4 + 2] = __shfl(r.z, b32 + g, 64);
    xrow[g * 4 + 3] = __shfl(r.w, b32 + g, 64);
  }
  if (lane < 16) {
    const float* sel = Wtab[rel * 2 + (lane >> 3)];   // lane<8: Wk ; lane>=8: Wq
    const int col = lane & 7;
    float a2 = sel[128 + col];
    #pragma unroll
    for (int j = 0; j < 16; ++j) a2 += xrow[j] * sel[j * 8 + col];
    if (lane < 8) {
      float* k2o = rel ? k2o1 : k2o0;
      k2o[node * 8 + col] = a2;
    } else {
      float* q2o = rel ? q2o1 : q2o0;
      q2o[node * 8 + col] = a2;
    }
  }
}

// ========= L2 GAT aggregation via z-trick (validated R13) =========
__global__ __launch_bounds__(256)
void agg_l2z_kernel(const int* __restrict__ rs, const int* __restrict__ cs,
                    const float* __restrict__ xA, const float* __restrict__ xB,
                    const float* __restrict__ k2a, const float* __restrict__ k2b,
                    const float* __restrict__ qt0, const float* __restrict__ qt1,
                    const float* __restrict__ Wv, const float* __restrict__ bv,
                    float* __restrict__ out) {
  __shared__ float Wv_lds[2][16 * 128];   // 16 KB
  __shared__ float z_lds[8][128];         // 4 KB
  __shared__ float bvs[2][16];            // sum over heads of bv
  const int tid = threadIdx.x;
  for (int i = tid; i < 2 * 16 * 128 / 4; i += 256)
    ((float4*)Wv_lds)[i] = ((const float4*)Wv)[i];
  if (tid < 32) {
    int rl = tid >> 4, o = tid & 15;
    float s = 0.f;
    #pragma unroll
    for (int h = 0; h < 8; ++h) s += bv[rl * 128 + h * 16 + o];
    bvs[rl][o] = s;
  }
  __syncthreads();

  int grp  = blockIdx.x * 8 + (tid >> 5);
  int lane = tid & 31;
  int gl   = tid >> 5;
  int rel  = grp >= N_NODES;
  int node = grp - (rel ? N_NODES : 0);
  const float* x  = rel ? xB : xA;
  const float* k2 = rel ? k2b : k2a;
  const float* qt = rel ? qt1 : qt0;

  int e0 = rs[grp], e1 = rs[grp + 1];
  const int h = lane >> 2, jg = (lane & 3) * 4;
  float qh = qt[node * 8 + h];
  float den = 0.f;
  float4 z = make_float4(0.f, 0.f, 0.f, 0.f);

  int e = e0;
  for (; e + 7 < e1; e += 8) {
    int s[8];
    #pragma unroll
    for (int j = 0; j < 8; ++j) s[j] = cs[e + j];
    float kv[8]; float4 xv[8];
    #pragma unroll
    for (int j = 0; j < 8; ++j) {
      kv[j] = k2[s[j] * 8 + h];
      xv[j] = *(const float4*)&x[(size_t)s[j] * 16 + jg];
    }
    #pragma unroll
    for (int j = 0; j < 8; ++j) {
      float sc = kv[j] + qh; sc = sc > 0.f ? sc : 0.2f * sc;
      float ex = __expf(sc);
      den += ex;
      z.x += ex * xv[j].x; z.y += ex * xv[j].y;
      z.z += ex * xv[j].z; z.w += ex * xv[j].w;
    }
  }
  for (; e < e1; ++e) {
    int s0 = cs[e];
    float kv = k2[s0 * 8 + h];
    float4 xv = *(const float4*)&x[(size_t)s0 * 16 + jg];
    float sc = kv + qh; sc = sc > 0.f ? sc : 0.2f * sc;
    float ex = __expf(sc);
    den += ex;
    z.x += ex * xv.x; z.y += ex * xv.y; z.z += ex * xv.z; z.w += ex * xv.w;
  }
  float inv = den > 0.f ? 1.f / den : 0.f;
  z.x *= inv; z.y *= inv; z.z *= inv; z.w *= inv;
  *(float4*)&z_lds[gl][h * 16 + jg] = z;
  __syncthreads();

  const int o = lane & 15, jh = (lane >> 4) * 8;
  const float* wv = Wv_lds[rel];
  float acc = 0.f;
  #pragma unroll
  for (int h2 = 0; h2 < 8; ++h2) {
    #pragma unroll
    for (int j = 0; j < 8; ++j)
      acc += z_lds[gl][h2 * 16 + jh + j] * wv[(jh + j) * 128 + h2 * 16 + o];
  }
  acc += __shfl_xor(acc, 16);
  if (lane < 16) {
    float r = 0.125f * (acc + ((e1 > e0) ? bvs[rel][o] : 0.f));
    float* ob = out + (rel ? 0 : (size_t)N_NODES * FEAT);
    ob[(size_t)node * FEAT + o] = r;
  }
}

extern "C" void kernel_launch(void* const* d_in, const int* in_sizes, int n_in,
                              void* d_out, int out_size, void* d_ws, size_t ws_size,
                              hipStream_t stream) {
  const int* idx_a  = (const int*)d_in[0];
  const int* idx_b  = (const int*)d_in[1];
  const int* src_r0 = (const int*)d_in[2];
  const int* dst_r0 = (const int*)d_in[3];
  const int* src_r1 = (const int*)d_in[4];
  const int* dst_r1 = (const int*)d_in[5];
  const float* emb_a = (const float*)d_in[6];
  const float* emb_b = (const float*)d_in[7];
  const float* l1_Wv = (const float*)d_in[8];
  const float* l1_bv = (const float*)d_in[9];
  const float* l1_Wq = (const float*)d_in[10];
  const float* l1_bq = (const float*)d_in[11];
  const float* l1_Wk = (const float*)d_in[12];
  const float* l1_bk = (const float*)d_in[13];
  const float* l2_Wv = (const float*)d_in[14];
  const float* l2_bv = (const float*)d_in[15];
  const float* l2_Wq = (const float*)d_in[16];
  const float* l2_bq = (const float*)d_in[17];
  const float* l2_Wk = (const float*)d_in[18];
  const float* l2_bk = (const float*)d_in[19];
  float* out = (float*)d_out;

  char* ws = (char*)d_ws;
  size_t off = 0;
  auto alloc = [&](size_t bytes) {
    void* p = ws + off; off += (bytes + 255) & ~255ULL; return p;
  };
  float* u0   = (float*)alloc((size_t)N_NODES * UST * 4);
  float* u1   = (float*)alloc((size_t)N_NODES * UST * 4);
  float* kb0  = (float*)alloc((size_t)N_NODES * HEADS * 4);
  float* kb1  = (float*)alloc((size_t)N_NODES * HEADS * 4);
  float* qb0  = (float*)alloc((size_t)N_NODES * HEADS * 4);
  float* qb1  = (float*)alloc((size_t)N_NODES * HEADS * 4);
  float* k2a  = (float*)alloc((size_t)N_NODES * HEADS * 4);
  float* k2b  = (float*)alloc((size_t)N_NODES * HEADS * 4);
  float* xA   = (float*)alloc((size_t)N_NODES * FEAT * 4);
  float* xB   = (float*)alloc((size_t)N_NODES * FEAT * 4);
  int*   rs   = (int*)  alloc((size_t)(2 * N_NODES + 1) * 4);
  int*   cs   = (int*)  alloc((size_t)2 * NEDGE * 4);
  int*   cnt  = (int*)  alloc((size_t)4 * N_NODES * 4);
  int*   bsum = (int*)  alloc(512 * 4);
  float* wf   = (float*)alloc(8 * 1040 * 4);

  dim3 blk(256);
  const int n2 = 2 * N_NODES;
  int* fill = cnt + n2;
  const int nScanBlk  = (n2 + 255) / 256;
  const int nEdgeBlk2 = (2 * NEDGE + 255) / 256;
  const int nAggBlk   = (n2 + 7) / 8;              // 12500 exactly (grid exact)
  const int nGemmBlk128 = (N_NODES + 127) / 128;   // 391
  const int nGemmBlk64  = (N_NODES + 63) / 64;

  fold_kernel<<<8, blk, 0, stream>>>(l1_Wv, l1_bv, l1_Wq, l1_bq, l1_Wk, l1_bk,
                                     l2_Wv, l2_bv, l2_Wq, l2_bq, l2_Wk, l2_bk, wf);
  auto wslot = [&](int layer, int rel, int qk) {
    return wf + (size_t)((layer << 2) | (rel << 1) | qk) * 1040;
  };

  hipMemsetAsync(cnt, 0, (size_t)2 * n2 * 4, stream);
  hist2_kernel<<<nEdgeBlk2, blk, 0, stream>>>(dst_r0, dst_r1, cnt);
  scan_bsum_kernel<<<nScanBlk, blk, 0, stream>>>(cnt, bsum, n2);
  scan_offsets_kernel<<<1, dim3(512), 0, stream>>>(bsum, nScanBlk);
  scan_final_kernel<<<nScanBlk, blk, 0, stream>>>(cnt, bsum, rs, n2);
  csr_scatter2_kernel<<<nEdgeBlk2, blk, 0, stream>>>(src_r0, dst_r0, src_r1, dst_r1,
                                                     rs, fill, cs);

  // ---- layer 1 (+ fused L2 qk in node_agg2) ----
  {
    gemm_v128_kernel<<<dim3(nGemmBlk128, 2), blk, 0, stream>>>(
        emb_a, idx_a, emb_b, idx_b, l1_Wv, l1_bv, u0, u1, N_NODES);
    qk_kernel<128, 132><<<dim3(nGemmBlk64, 2), blk, 0, stream>>>(
        emb_a, idx_a, emb_b, idx_b,
        wslot(0,0,1), wslot(0,1,0), wslot(0,1,1), wslot(0,0,0),
        kb0, kb1, qb1, qb0, N_NODES);
    // rel0 groups produce xB: k2b via wslot(1,1,1), qb0 via wslot(1,0,0)
    // rel1 groups produce xA: k2a via wslot(1,0,1), qb1 via wslot(1,1,0)
    node_agg2_kernel<<<nAggBlk, blk, 0, stream>>>(
        rs, cs, u0, u1, kb0, kb1, qb0, qb1, xB, xA,
        wslot(1,1,1), wslot(1,0,0), wslot(1,0,1), wslot(1,1,0),
        k2b, qb0, k2a, qb1);
  }
  // ---- layer 2 (z-trick) ----
  {
    agg_l2z_kernel<<<nAggBlk, blk, 0, stream>>>(
        rs, cs, xA, xB, k2a, k2b, qb0, qb1, l2_Wv, l2_bv, out);
  }
}

// Round 18
// 330.904 us; speedup vs baseline: 1.1268x; 1.1268x over previous
//
#include <hip/hip_runtime.h>
#include <hip/hip_fp16.h>

#define N_NODES 50000
#define NEDGE   500000
#define HEADS   8
#define FEAT    16
#define HF      128   // HEADS*FEAT
#define UST     64    // u row stride in FLOATS: 128 fp16 = 256B

typedef __attribute__((ext_vector_type(8))) _Float16 half8;
typedef __attribute__((ext_vector_type(4))) float floatx4;

__device__ __forceinline__ unsigned pkh2(float a, float b) {
  __half2 h = __floats2half2_rn(a, b);
  return *(unsigned*)&h;
}

// ========== prep: Wt[side][col][k] fp16 <- W[side][k][col] fp32 (grid 2) ==========
__global__ __launch_bounds__(256)
void prep_wt_kernel(const float* __restrict__ W, __half* __restrict__ Wt) {
  int side = blockIdx.x;
  const float* Wp = W + (size_t)side * 16384;
  __half* o = Wt + (size_t)side * 16384;
  for (int j = threadIdx.x; j < 16384; j += 256) {
    int k = j >> 7, col = j & 127;      // read coalesced over j
    o[col * 128 + k] = __float2half(Wp[j]);
  }
}

// ========== MFMA GEMM: u(fp16) = x[idx] @ W + b ; grid (782, 2) ==========
// 64 rows/block, 4 waves x 16 rows. A (fp32->fp16) and Wt reg-staged into
// XOR-swizzled LDS (byte ^= (row&7)<<4; write AND read swizzled - rule #21),
// ONE barrier, then 8 col-tiles x 4 K-steps of v_mfma_f32_16x16x32_f16.
// Fragments: A lane=(row=L&15, k=(L>>4)*8+e); B mirrored (col=L&15);
// D col=L&15, row=(L>>4)*4+reg (m89-verified). Bias preloaded into C.
__global__ __launch_bounds__(256)
void gemm_mfma_kernel(const float* __restrict__ xa, const int* __restrict__ idxa,
                      const float* __restrict__ xb, const int* __restrict__ idxb,
                      const __half* __restrict__ Wt, const float* __restrict__ bias,
                      float* __restrict__ ua, float* __restrict__ ub, int nrows) {
  const int side = blockIdx.y;
  const float* x  = side ? xb : xa;
  const int* idx  = side ? idxb : idxa;
  const __half* Wtp = Wt + (size_t)side * 16384;
  const float* bp = bias + side * HF;
  float* uout = side ? ub : ua;

  __shared__ __align__(16) unsigned short sm[24576];  // A 16KB | Wt 32KB
  char* Asm = (char*)sm;
  char* Wsm = (char*)(sm + 8192);
  const int tid = threadIdx.x;
  const int w = tid >> 6, lane = tid & 63;
  const int row0 = blockIdx.x * 64;

  // ---- stage Wt: 2048 x 16B pieces (8/thread), swizzled ----
  #pragma unroll
  for (int p = 0; p < 8; ++p) {
    int i = p * 256 + tid;
    int col = i >> 4, kp = i & 15;
    float4 v = *(const float4*)(Wtp + col * 128 + kp * 8);   // 8 f16 = 16B
    int dst = (col * 256 + kp * 16) ^ ((col & 7) << 4);
    *(float4*)(Wsm + dst) = v;
  }
  // ---- stage A: fp32 -> fp16, swizzled ----
  {
    int r = tid >> 2;
    int rr = row0 + r;
    int g = (rr < nrows) ? (idx ? idx[rr] : rr) : 0;
    const float* xp = x + (size_t)g * 128 + (tid & 3) * 8;
    #pragma unroll
    for (int p = 0; p < 4; ++p) {
      float4 v0 = *(const float4*)(xp + p * 32);
      float4 v1 = *(const float4*)(xp + p * 32 + 4);
      uint4 o;
      o.x = pkh2(v0.x, v0.y); o.y = pkh2(v0.z, v0.w);
      o.z = pkh2(v1.x, v1.y); o.w = pkh2(v1.z, v1.w);
      int k0 = (tid & 3) * 8 + p * 32;
      int dst = (r * 256 + k0 * 2) ^ ((r & 7) << 4);
      *(uint4*)(Asm + dst) = o;
    }
  }
  __syncthreads();   // only barrier

  floatx4 acc[8];
  #pragma unroll
  for (int t = 0; t < 8; ++t) {
    float b = bp[t * 16 + (lane & 15)];
    acc[t] = (floatx4){b, b, b, b};
  }

  const int lrow = lane & 15, lk = lane >> 4;
  #pragma unroll
  for (int kb = 0; kb < 4; ++kb) {
    int r = w * 16 + lrow;
    int abyte = (r * 256 + kb * 64 + lk * 16) ^ ((r & 7) << 4);
    half8 af = *(const half8*)(Asm + abyte);
    #pragma unroll
    for (int t = 0; t < 8; ++t) {
      int c = t * 16 + lrow;
      int bbyte = (c * 256 + kb * 64 + lk * 16) ^ ((c & 7) << 4);
      half8 bf = *(const half8*)(Wsm + bbyte);
      acc[t] = __builtin_amdgcn_mfma_f32_16x16x32_f16(af, bf, acc[t], 0, 0, 0);
    }
  }

  // ---- epilogue: D col=lane&15, row=(lane>>4)*4+j ; u fp16 scalar stores ----
  unsigned short* up = (unsigned short*)uout;
  #pragma unroll
  for (int j = 0; j < 4; ++j) {
    int rr = row0 + w * 16 + (lane >> 4) * 4 + j;
    if (rr < nrows) {
      #pragma unroll
      for (int t = 0; t < 8; ++t) {
        __half h = __float2half(acc[t][j]);
        up[(size_t)rr * 128 + t * 16 + (lane & 15)] = *(unsigned short*)&h;
      }
    }
  }
}

// ================= fold Wf = Wv @ Wqk [Kx,8], bias bf = bv@Wqk + bqk =================
__global__ __launch_bounds__(256)
void fold_kernel(const float* __restrict__ l1_Wv, const float* __restrict__ l1_bv,
                 const float* __restrict__ l1_Wq, const float* __restrict__ l1_bq,
                 const float* __restrict__ l1_Wk, const float* __restrict__ l1_bk,
                 const float* __restrict__ l2_Wv, const float* __restrict__ l2_bv,
                 const float* __restrict__ l2_Wq, const float* __restrict__ l2_bq,
                 const float* __restrict__ l2_Wk, const float* __restrict__ l2_bk,
                 float* __restrict__ outbuf) {
  int b = blockIdx.x;
  int layer = b >> 2, rel = (b >> 1) & 1, qk = b & 1;
  int Kx = (layer == 0) ? 128 : 16;
  const float* Wv = ((layer == 0) ? l1_Wv : l2_Wv) + (size_t)rel * Kx * HF;
  const float* bv = ((layer == 0) ? l1_bv : l2_bv) + rel * HF;
  const float* Wqk = ((layer == 0) ? (qk ? l1_Wk : l1_Wq) : (qk ? l2_Wk : l2_Wq)) + (size_t)rel * HF * 8;
  const float* bqk = ((layer == 0) ? (qk ? l1_bk : l1_bq) : (qk ? l2_bk : l2_bq)) + rel * 8;
  float* o = outbuf + (size_t)b * 1040;
  for (int t = threadIdx.x; t < Kx * 8; t += 256) {
    int row = t >> 3, c = t & 7;
    float acc = 0.f;
    for (int j = 0; j < HF; ++j) acc += Wv[row * HF + j] * Wqk[j * 8 + c];
    o[t] = acc;
  }
  for (int t = threadIdx.x; t < 8; t += 256) {
    float acc = bqk[t];
    for (int j = 0; j < HF; ++j) acc += bv[j] * Wqk[j * 8 + t];
    o[Kx * 8 + t] = acc;
  }
}

// ========== L1 qk projections: k -> kb[N,8] fp32, q -> qout[N,8]; grid (nb,2) ==========
template<int K, int SA>
__global__ __launch_bounds__(256)
void qk_kernel(const float* __restrict__ xa, const int* __restrict__ idxa,
               const float* __restrict__ xb, const int* __restrict__ idxb,
               const float* __restrict__ WfkA, const float* __restrict__ WfqA,
               const float* __restrict__ WfkB, const float* __restrict__ WfqB,
               float* __restrict__ kA, float* __restrict__ kB,
               float* __restrict__ qA, float* __restrict__ qB, int nrows) {
  const int side = blockIdx.y;
  const float* x   = side ? xb : xa;
  const int* idx   = side ? idxb : idxa;
  const float* Wfk = side ? WfkB : WfkA;
  const float* Wfq = side ? WfqB : WfqA;
  float* kout = side ? kB : kA;
  float* qout = side ? qB : qA;

  __shared__ float x_lds[64 * SA];
  __shared__ float Wk_lds[K * 8 + 8];
  __shared__ float Wq_lds[K * 8 + 8];
  const int tid = threadIdx.x;
  const int row0 = blockIdx.x * 64;
  for (int i = tid; i < K * 8 + 8; i += 256) { Wk_lds[i] = Wfk[i]; Wq_lds[i] = Wfq[i]; }
  {
    int rr = row0 + (tid >> 2);
    int g = (rr < nrows) ? (idx ? idx[rr] : rr) : -1;
    const float* xp = (g >= 0) ? x + (size_t)g * K : nullptr;
    #pragma unroll
    for (int j = 0; j < K / 16; ++j) {
      int c = (tid & 3) * 4 + j * 16;
      float4 v = xp ? *(const float4*)(xp + c) : make_float4(0.f,0.f,0.f,0.f);
      *(float4*)&x_lds[(tid >> 2) * SA + c] = v;
    }
  }
  __syncthreads();
  const int r = tid >> 2, grp = tid & 3;
  const float* wsel = (grp < 2) ? Wk_lds : Wq_lds;
  const int c0 = (grp & 1) * 4;
  float acc[4];
  #pragma unroll
  for (int cc = 0; cc < 4; ++cc) acc[cc] = wsel[K * 8 + c0 + cc];
  #pragma unroll 4
  for (int k4 = 0; k4 < K / 4; ++k4) {
    float4 a4 = *(float4*)&x_lds[r * SA + k4 * 4];
    float av[4] = {a4.x, a4.y, a4.z, a4.w};
    #pragma unroll
    for (int j = 0; j < 4; ++j) {
      float4 w = *(float4*)&wsel[(k4 * 4 + j) * 8 + c0];
      acc[0] += av[j] * w.x; acc[1] += av[j] * w.y;
      acc[2] += av[j] * w.z; acc[3] += av[j] * w.w;
    }
  }
  int rr = row0 + r;
  if (rr < nrows) {
    if (grp < 2)
      *(float4*)&kout[(size_t)rr * 8 + grp * 4] = *(float4*)acc;
    else
      *(float4*)&qout[(size_t)rr * 8 + (grp - 2) * 4] = *(float4*)acc;
  }
}

// ========== L2 qk: k2 = x@Wfk, q = x@Wfq ([n,16] -> [n,8] each) ; grid (nb,2) ==========
__global__ __launch_bounds__(256)
void qk16_kernel(const float* __restrict__ xA, const float* __restrict__ xB,
                 const float* __restrict__ WfkA, const float* __restrict__ WfqA,
                 const float* __restrict__ WfkB, const float* __restrict__ WfqB,
                 float* __restrict__ k2a, float* __restrict__ k2b,
                 float* __restrict__ qA, float* __restrict__ qB, int n) {
  const int side = blockIdx.y;
  const float* x   = side ? xB : xA;
  const float* Wfk = side ? WfkB : WfkA;
  const float* Wfq = side ? WfqB : WfqA;
  float* k2  = side ? k2b : k2a;
  float* qout = side ? qB : qA;
  __shared__ float Wk[136], Wq[136];
  const int tid = threadIdx.x;
  for (int i = tid; i < 136; i += 256) { Wk[i] = Wfk[i]; Wq[i] = Wfq[i]; }
  __syncthreads();
  int row = blockIdx.x * 32 + (tid >> 3), col = tid & 7;
  if (row >= n) return;
  const float* xr = x + (size_t)row * 16;
  float ak = Wk[128 + col], aq = Wq[128 + col];
  #pragma unroll
  for (int j4 = 0; j4 < 4; ++j4) {
    float4 v = *(const float4*)(xr + j4 * 4);
    float xv[4] = {v.x, v.y, v.z, v.w};
    #pragma unroll
    for (int j = 0; j < 4; ++j) {
      ak += xv[j] * Wk[(j4 * 4 + j) * 8 + col];
      aq += xv[j] * Wq[(j4 * 4 + j) * 8 + col];
    }
  }
  k2[row * 8 + col] = ak;
  qout[row * 8 + col] = aq;
}

// ================= batched CSR build (both relations at once) =================
__global__ __launch_bounds__(256)
void hist2_kernel(const int* __restrict__ dst0, const int* __restrict__ dst1,
                  int* __restrict__ cnt) {
  int e = blockIdx.x * 256 + threadIdx.x;
  if (e < NEDGE) atomicAdd(&cnt[dst0[e]], 1);
  else if (e < 2 * NEDGE) atomicAdd(&cnt[N_NODES + dst1[e - NEDGE]], 1);
}

__global__ __launch_bounds__(256)
void scan_bsum_kernel(const int* __restrict__ cnt, int* __restrict__ bsum, int n) {
  __shared__ int s[256];
  int i = blockIdx.x * 256 + threadIdx.x;
  s[threadIdx.x] = (i < n) ? cnt[i] : 0;
  __syncthreads();
  for (int o = 128; o > 0; o >>= 1) {
    if (threadIdx.x < o) s[threadIdx.x] += s[threadIdx.x + o];
    __syncthreads();
  }
  if (threadIdx.x == 0) bsum[blockIdx.x] = s[0];
}

__global__ __launch_bounds__(512)
void scan_offsets_kernel(int* __restrict__ bsum, int nb) {
  __shared__ int s[512];
  int t = threadIdx.x;
  s[t] = (t < nb) ? bsum[t] : 0;
  __syncthreads();
  for (int o = 1; o < 512; o <<= 1) {
    int v = (t >= o) ? s[t - o] : 0;
    __syncthreads();
    s[t] += v;
    __syncthreads();
  }
  if (t < nb) bsum[t] = (t == 0) ? 0 : s[t - 1];
}

__global__ __launch_bounds__(256)
void scan_final_kernel(const int* __restrict__ cnt, const int* __restrict__ boff,
                       int* __restrict__ row_start, int n) {
  __shared__ int s[256];
  int t = threadIdx.x, i = blockIdx.x * 256 + t;
  int v = (i < n) ? cnt[i] : 0;
  s[t] = v;
  __syncthreads();
  for (int o = 1; o < 256; o <<= 1) {
    int w = (t >= o) ? s[t - o] : 0;
    __syncthreads();
    s[t] += w;
    __syncthreads();
  }
  if (i < n)  row_start[i] = boff[blockIdx.x] + s[t] - v;
  if (i == n - 1) row_start[n] = boff[blockIdx.x] + s[t];
}

__global__ __launch_bounds__(256)
void csr_scatter2_kernel(const int* __restrict__ s0, const int* __restrict__ d0,
                         const int* __restrict__ s1, const int* __restrict__ d1,
                         const int* __restrict__ rs, int* __restrict__ fill,
                         int* __restrict__ cs) {
  int e = blockIdx.x * 256 + threadIdx.x;
  if (e >= 2 * NEDGE) return;
  int rel = (e >= NEDGE);
  int ee = rel ? e - NEDGE : e;
  int d = rel ? d1[ee] : d0[ee];
  int s = rel ? s1[ee] : s0[ee];
  int key = rel * N_NODES + d;
  int pos = rs[key] + atomicAdd(&fill[key], 1);
  cs[pos] = s;
}

// ========= L1 GAT aggregation, 32 lanes/node, fp16 u (uint2/lane), separate fp32 k ====
__global__ __launch_bounds__(256)
void node_agg2_kernel(const int* __restrict__ rs, const int* __restrict__ cs,
                      const float* __restrict__ u0, const float* __restrict__ u1,
                      const float* __restrict__ kb0, const float* __restrict__ kb1,
                      const float* __restrict__ qt0, const float* __restrict__ qt1,
                      float* __restrict__ out0, float* __restrict__ out1, int elu) {
  int grp  = (blockIdx.x * 256 + threadIdx.x) >> 5;
  int lane = threadIdx.x & 31;
  if (grp >= 2 * N_NODES) return;
  int rel = grp >= N_NODES;
  int node = grp - (rel ? N_NODES : 0);
  const float* ut = rel ? u1 : u0;
  const float* kb = rel ? kb1 : kb0;
  const float* qt = rel ? qt1 : qt0;
  float* out      = rel ? out1 : out0;

  int e0 = rs[grp], e1 = rs[grp + 1];
  const int hd = lane >> 2;
  float qh = qt[node * 8 + hd];
  float den = 0.f;
  float4 acc = make_float4(0.f, 0.f, 0.f, 0.f);

  int e = e0;
  for (; e + 7 < e1; e += 8) {
    int s[8];
    #pragma unroll
    for (int j = 0; j < 8; ++j) s[j] = cs[e + j];
    uint2 uv[8]; float kv[8];
    #pragma unroll
    for (int j = 0; j < 8; ++j) {
      uv[j] = *(const uint2*)((const char*)(ut + (size_t)s[j] * UST) + lane * 8);
      kv[j] = kb[s[j] * 8 + hd];
    }
    #pragma unroll
    for (int j = 0; j < 8; ++j) {
      float sc = kv[j] + qh; sc = sc > 0.f ? sc : 0.2f * sc;
      float ex = __expf(sc);
      den += ex;
      float2 f01 = __half22float2(*(__half2*)&uv[j].x);
      float2 f23 = __half22float2(*(__half2*)&uv[j].y);
      acc.x += ex * f01.x; acc.y += ex * f01.y;
      acc.z += ex * f23.x; acc.w += ex * f23.y;
    }
  }
  for (; e < e1; ++e) {
    int s0 = cs[e];
    uint2 uvv = *(const uint2*)((const char*)(ut + (size_t)s0 * UST) + lane * 8);
    float kv = kb[s0 * 8 + hd];
    float sc = kv + qh; sc = sc > 0.f ? sc : 0.2f * sc;
    float ex = __expf(sc);
    den += ex;
    float2 f01 = __half22float2(*(__half2*)&uvv.x);
    float2 f23 = __half22float2(*(__half2*)&uvv.y);
    acc.x += ex * f01.x; acc.y += ex * f01.y;
    acc.z += ex * f23.x; acc.w += ex * f23.y;
  }
  float inv = den > 0.f ? 1.f / den : 0.f;
  float4 r = make_float4(acc.x * inv, acc.y * inv, acc.z * inv, acc.w * inv);
  #pragma unroll
  for (int m = 4; m <= 16; m <<= 1) {
    r.x += __shfl_xor(r.x, m); r.y += __shfl_xor(r.y, m);
    r.z += __shfl_xor(r.z, m); r.w += __shfl_xor(r.w, m);
  }
  r.x *= 0.125f; r.y *= 0.125f; r.z *= 0.125f; r.w *= 0.125f;
  if (elu) {
    r.x = r.x > 0.f ? r.x : expm1f(r.x);
    r.y = r.y > 0.f ? r.y : expm1f(r.y);
    r.z = r.z > 0.f ? r.z : expm1f(r.z);
    r.w = r.w > 0.f ? r.w : expm1f(r.w);
  }
  if (lane < 4) *(float4*)&out[(size_t)node * FEAT + lane * 4] = r;
}

// ========= L2 GAT aggregation via z-trick (validated R13) =========
__global__ __launch_bounds__(256)
void agg_l2z_kernel(const int* __restrict__ rs, const int* __restrict__ cs,
                    const float* __restrict__ xA, const float* __restrict__ xB,
                    const float* __restrict__ k2a, const float* __restrict__ k2b,
                    const float* __restrict__ qt0, const float* __restrict__ qt1,
                    const float* __restrict__ Wv, const float* __restrict__ bv,
                    float* __restrict__ out) {
  __shared__ float Wv_lds[2][16 * 128];   // 16 KB
  __shared__ float z_lds[8][128];         // 4 KB
  __shared__ float bvs[2][16];
  const int tid = threadIdx.x;
  for (int i = tid; i < 2 * 16 * 128 / 4; i += 256)
    ((float4*)Wv_lds)[i] = ((const float4*)Wv)[i];
  if (tid < 32) {
    int rl = tid >> 4, o = tid & 15;
    float s = 0.f;
    #pragma unroll
    for (int h = 0; h < 8; ++h) s += bv[rl * 128 + h * 16 + o];
    bvs[rl][o] = s;
  }
  __syncthreads();

  int grp  = blockIdx.x * 8 + (tid >> 5);
  int lane = tid & 31;
  int gl   = tid >> 5;
  int rel  = grp >= N_NODES;
  int node = grp - (rel ? N_NODES : 0);
  const float* x  = rel ? xB : xA;
  const float* k2 = rel ? k2b : k2a;
  const float* qt = rel ? qt1 : qt0;

  int e0 = rs[grp], e1 = rs[grp + 1];
  const int h = lane >> 2, jg = (lane & 3) * 4;
  float qh = qt[node * 8 + h];
  float den = 0.f;
  float4 z = make_float4(0.f, 0.f, 0.f, 0.f);

  int e = e0;
  for (; e + 7 < e1; e += 8) {
    int s[8];
    #pragma unroll
    for (int j = 0; j < 8; ++j) s[j] = cs[e + j];
    float kv[8]; float4 xv[8];
    #pragma unroll
    for (int j = 0; j < 8; ++j) {
      kv[j] = k2[s[j] * 8 + h];
      xv[j] = *(const float4*)&x[(size_t)s[j] * 16 + jg];
    }
    #pragma unroll
    for (int j = 0; j < 8; ++j) {
      float sc = kv[j] + qh; sc = sc > 0.f ? sc : 0.2f * sc;
      float ex = __expf(sc);
      den += ex;
      z.x += ex * xv[j].x; z.y += ex * xv[j].y;
      z.z += ex * xv[j].z; z.w += ex * xv[j].w;
    }
  }
  for (; e < e1; ++e) {
    int s0 = cs[e];
    float kv = k2[s0 * 8 + h];
    float4 xv = *(const float4*)&x[(size_t)s0 * 16 + jg];
    float sc = kv + qh; sc = sc > 0.f ? sc : 0.2f * sc;
    float ex = __expf(sc);
    den += ex;
    z.x += ex * xv.x; z.y += ex * xv.y; z.z += ex * xv.z; z.w += ex * xv.w;
  }
  float inv = den > 0.f ? 1.f / den : 0.f;
  z.x *= inv; z.y *= inv; z.z *= inv; z.w *= inv;
  *(float4*)&z_lds[gl][h * 16 + jg] = z;
  __syncthreads();

  const int o = lane & 15, jh = (lane >> 4) * 8;
  const float* wv = Wv_lds[rel];
  float acc = 0.f;
  #pragma unroll
  for (int h2 = 0; h2 < 8; ++h2) {
    #pragma unroll
    for (int j = 0; j < 8; ++j)
      acc += z_lds[gl][h2 * 16 + jh + j] * wv[(jh + j) * 128 + h2 * 16 + o];
  }
  acc += __shfl_xor(acc, 16);
  if (lane < 16) {
    float r = 0.125f * (acc + ((e1 > e0) ? bvs[rel][o] : 0.f));
    float* ob = out + (rel ? 0 : (size_t)N_NODES * FEAT);
    ob[(size_t)node * FEAT + o] = r;
  }
}

extern "C" void kernel_launch(void* const* d_in, const int* in_sizes, int n_in,
                              void* d_out, int out_size, void* d_ws, size_t ws_size,
                              hipStream_t stream) {
  const int* idx_a  = (const int*)d_in[0];
  const int* idx_b  = (const int*)d_in[1];
  const int* src_r0 = (const int*)d_in[2];
  const int* dst_r0 = (const int*)d_in[3];
  const int* src_r1 = (const int*)d_in[4];
  const int* dst_r1 = (const int*)d_in[5];
  const float* emb_a = (const float*)d_in[6];
  const float* emb_b = (const float*)d_in[7];
  const float* l1_Wv = (const float*)d_in[8];
  const float* l1_bv = (const float*)d_in[9];
  const float* l1_Wq = (const float*)d_in[10];
  const float* l1_bq = (const float*)d_in[11];
  const float* l1_Wk = (const float*)d_in[12];
  const float* l1_bk = (const float*)d_in[13];
  const float* l2_Wv = (const float*)d_in[14];
  const float* l2_bv = (const float*)d_in[15];
  const float* l2_Wq = (const float*)d_in[16];
  const float* l2_bq = (const float*)d_in[17];
  const float* l2_Wk = (const float*)d_in[18];
  const float* l2_bk = (const float*)d_in[19];
  float* out = (float*)d_out;

  char* ws = (char*)d_ws;
  size_t off = 0;
  auto alloc = [&](size_t bytes) {
    void* p = ws + off; off += (bytes + 255) & ~255ULL; return p;
  };
  float*  u0   = (float*)alloc((size_t)N_NODES * UST * 4);
  float*  u1   = (float*)alloc((size_t)N_NODES * UST * 4);
  __half* Wt   = (__half*)alloc(2 * 16384 * 2);            // transposed fp16 L1 Wv
  float*  kb0  = (float*)alloc((size_t)N_NODES * HEADS * 4);
  float*  kb1  = (float*)alloc((size_t)N_NODES * HEADS * 4);
  float*  qb0  = (float*)alloc((size_t)N_NODES * HEADS * 4);
  float*  qb1  = (float*)alloc((size_t)N_NODES * HEADS * 4);
  float*  k2a  = (float*)alloc((size_t)N_NODES * HEADS * 4);
  float*  k2b  = (float*)alloc((size_t)N_NODES * HEADS * 4);
  float*  xA   = (float*)alloc((size_t)N_NODES * FEAT * 4);
  float*  xB   = (float*)alloc((size_t)N_NODES * FEAT * 4);
  int*    rs   = (int*)  alloc((size_t)(2 * N_NODES + 1) * 4);
  int*    cs   = (int*)  alloc((size_t)2 * NEDGE * 4);
  int*    cnt  = (int*)  alloc((size_t)4 * N_NODES * 4);
  int*    bsum = (int*)  alloc(512 * 4);
  float*  wf   = (float*)alloc(8 * 1040 * 4);

  dim3 blk(256);
  const int n2 = 2 * N_NODES;
  int* fill = cnt + n2;
  const int nScanBlk  = (n2 + 255) / 256;
  const int nEdgeBlk2 = (2 * NEDGE + 255) / 256;
  const int nAggBlk   = (n2 + 7) / 8;
  const int nGemmBlk64 = (N_NODES + 63) / 64;      // 782
  const int nQk16Blk   = (N_NODES + 31) / 32;

  fold_kernel<<<8, blk, 0, stream>>>(l1_Wv, l1_bv, l1_Wq, l1_bq, l1_Wk, l1_bk,
                                     l2_Wv, l2_bv, l2_Wq, l2_bq, l2_Wk, l2_bk, wf);
  prep_wt_kernel<<<2, blk, 0, stream>>>(l1_Wv, Wt);
  auto wslot = [&](int layer, int rel, int qk) {
    return wf + (size_t)((layer << 2) | (rel << 1) | qk) * 1040;
  };

  hipMemsetAsync(cnt, 0, (size_t)2 * n2 * 4, stream);
  hist2_kernel<<<nEdgeBlk2, blk, 0, stream>>>(dst_r0, dst_r1, cnt);
  scan_bsum_kernel<<<nScanBlk, blk, 0, stream>>>(cnt, bsum, n2);
  scan_offsets_kernel<<<1, dim3(512), 0, stream>>>(bsum, nScanBlk);
  scan_final_kernel<<<nScanBlk, blk, 0, stream>>>(cnt, bsum, rs, n2);
  csr_scatter2_kernel<<<nEdgeBlk2, blk, 0, stream>>>(src_r0, dst_r0, src_r1, dst_r1,
                                                     rs, fill, cs);

  // ---- layer 1 ----
  {
    gemm_mfma_kernel<<<dim3(nGemmBlk64, 2), blk, 0, stream>>>(
        emb_a, idx_a, emb_b, idx_b, Wt, l1_bv, u0, u1, N_NODES);
    qk_kernel<128, 132><<<dim3(nGemmBlk64, 2), blk, 0, stream>>>(
        emb_a, idx_a, emb_b, idx_b,
        wslot(0,0,1), wslot(0,1,0), wslot(0,1,1), wslot(0,0,0),
        kb0, kb1, qb1, qb0, N_NODES);
    node_agg2_kernel<<<nAggBlk, blk, 0, stream>>>(rs, cs, u0, u1, kb0, kb1,
                                                  qb0, qb1, xB, xA, 1);
  }
  // ---- layer 2 (z-trick) ----
  {
    qk16_kernel<<<dim3(nQk16Blk, 2), blk, 0, stream>>>(
        xA, xB,
        wslot(1,0,1), wslot(1,1,0), wslot(1,1,1), wslot(1,0,0),
        k2a, k2b, qb1, qb0, N_NODES);
    agg_l2z_kernel<<<nAggBlk, blk, 0, stream>>>(
        rs, cs, xA, xB, k2a, k2b, qb0, qb1, l2_Wv, l2_bv, out);
  }
}